// Round 12
// baseline (509.600 us; speedup 1.0000x reference)
//
#include <hip/hip_runtime.h>
#include <math.h>

// ---------------------------------------------------------------------------
// Transformer encoder block, bf16 MFMA compute, fp32 I/O.
// B=4 S=2048 H=1024 NH=16 HD=64 FF=4096
// ---------------------------------------------------------------------------

typedef unsigned short u16;
typedef unsigned int   u32;
typedef __attribute__((ext_vector_type(4)))  float f32x4;
typedef __attribute__((ext_vector_type(16))) float f32x16;
typedef __attribute__((ext_vector_type(8)))  short short8;
typedef __attribute__((ext_vector_type(4)))  short short4v;

__device__ __forceinline__ u16 f2bf(float f){
  union { float f; u32 u; } v; v.f = f;
  u32 u = v.u;
  return (u16)((u + 0x7fffu + ((u >> 16) & 1u)) >> 16);   // RNE
}
__device__ __forceinline__ float bf2f(u16 h){
  union { u32 u; float f; } v; v.u = ((u32)h) << 16;
  return v.f;
}

__device__ __forceinline__ void async16(const u16* g, u16* l){
  __builtin_amdgcn_global_load_lds((const __attribute__((address_space(1))) u32*)g,
                                   (__attribute__((address_space(3))) u32*)l, 16, 0, 0);
}

__device__ __forceinline__ u32 cvt_pk_bf16(float lo, float hi){
  u32 r;
  asm("v_cvt_pk_bf16_f32 %0, %1, %2" : "=v"(r) : "v"(lo), "v"(hi));
  return r;
}

__device__ __forceinline__ float fexp2(float x){   // native 2^x, guaranteed
  float r;
  asm("v_exp_f32 %0, %1" : "=v"(r) : "v"(x));
  return r;
}

__device__ __forceinline__ short8 frag4(u32 a, u32 b, u32 c, u32 d){
  union { u32 u[4]; short8 s; } x;
  x.u[0] = a; x.u[1] = b; x.u[2] = c; x.u[3] = d;
  return x.s;
}

// ---------------------------------------------------------------------------
// prep: fused weight fp32->bf16 convert + bias concat + LayerNorm1.
// blocks [0, 12291): convert chunks; blocks [12291, 20483): LN1 rows.
// ---------------------------------------------------------------------------
__global__ __launch_bounds__(256) void k_prep(
    const float* __restrict__ Wq, const float* __restrict__ Wk,
    const float* __restrict__ Wv, const float* __restrict__ Wo,
    const float* __restrict__ Wm1, const float* __restrict__ Wm2,
    const float* __restrict__ bq, const float* __restrict__ bk,
    const float* __restrict__ bv,
    u16* __restrict__ wqkv, u16* __restrict__ wo,
    u16* __restrict__ wm1, u16* __restrict__ wm2, float* __restrict__ bqkv,
    const float* __restrict__ x, const float* __restrict__ g1,
    const float* __restrict__ b1, u16* __restrict__ nrm){
  __shared__ float ps[4], pq[4];
  const int t = threadIdx.x;
  if (blockIdx.x >= 12291){
    // ---- LN1 row ----
    int row = blockIdx.x - 12291;
    const float* xr = x + (size_t)row * 1024;
    float4 v = ((const float4*)xr)[t];
    float s = v.x + v.y + v.z + v.w;
    float q = v.x*v.x + v.y*v.y + v.z*v.z + v.w*v.w;
    #pragma unroll
    for (int off = 1; off < 64; off <<= 1){
      s += __shfl_xor(s, off);
      q += __shfl_xor(q, off);
    }
    int w = t >> 6, l = t & 63;
    if (l == 0){ ps[w] = s; pq[w] = q; }
    __syncthreads();
    s = ps[0] + ps[1] + ps[2] + ps[3];
    q = pq[0] + pq[1] + pq[2] + pq[3];
    float mean = s * (1.0f/1024.0f);
    float var  = q * (1.0f/1024.0f) - mean*mean;
    float rstd = rsqrtf(var + 1e-5f);
    float4 gv = ((const float4*)g1)[t];
    float4 bv4 = ((const float4*)b1)[t];
    ushort4 o;
    o.x = f2bf((v.x - mean)*rstd*gv.x + bv4.x);
    o.y = f2bf((v.y - mean)*rstd*gv.y + bv4.y);
    o.z = f2bf((v.z - mean)*rstd*gv.z + bv4.z);
    o.w = f2bf((v.w - mean)*rstd*gv.w + bv4.w);
    ((ushort4*)(nrm + (size_t)row * 1024))[t] = o;
    return;
  }
  // ---- weight convert ----
  int c = blockIdx.x * 256 + t;
  const float* src; u16* dst;
  if      (c <  262144){ src = Wq  + c*4;             dst = wqkv + c*4; }
  else if (c <  524288){ src = Wk  + (c-262144)*4;    dst = wqkv + 1048576 + (c-262144)*4; }
  else if (c <  786432){ src = Wv  + (c-524288)*4;    dst = wqkv + 2097152 + (c-524288)*4; }
  else if (c < 1048576){ src = Wo  + (c-786432)*4;    dst = wo  + (c-786432)*4; }
  else if (c < 2097152){ src = Wm1 + (c-1048576)*4;   dst = wm1 + (c-1048576)*4; }
  else if (c < 3145728){ src = Wm2 + (c-2097152)*4;   dst = wm2 + (c-2097152)*4; }
  else if (c < 3146496){
    int i = (c - 3145728)*4;
    const float* bsrc = i < 1024 ? bq + i : (i < 2048 ? bk + i - 1024 : bv + i - 2048);
    *(float4*)(bqkv + i) = *(const float4*)bsrc;
    return;
  } else return;
  float4 v = *(const float4*)src;
  ushort4 o; o.x = f2bf(v.x); o.y = f2bf(v.y); o.z = f2bf(v.z); o.w = f2bf(v.w);
  *(ushort4*)dst = o;
}

// ---------------------------------------------------------------------------
// LayerNorm: fp32 [rows][1024] -> bf16 [rows][1024]. one block per row. (LN2)
// ---------------------------------------------------------------------------
__global__ __launch_bounds__(256) void k_ln(const float* __restrict__ x,
                                            const float* __restrict__ g,
                                            const float* __restrict__ b,
                                            u16* __restrict__ out){
  int row = blockIdx.x;
  int t = threadIdx.x;
  const float* xr = x + (size_t)row * 1024;
  float4 v = ((const float4*)xr)[t];
  float s = v.x + v.y + v.z + v.w;
  float q = v.x*v.x + v.y*v.y + v.z*v.z + v.w*v.w;
  #pragma unroll
  for (int off = 1; off < 64; off <<= 1){
    s += __shfl_xor(s, off);
    q += __shfl_xor(q, off);
  }
  __shared__ float ps[4], pq[4];
  int w = t >> 6, l = t & 63;
  if (l == 0){ ps[w] = s; pq[w] = q; }
  __syncthreads();
  s = ps[0] + ps[1] + ps[2] + ps[3];
  q = pq[0] + pq[1] + pq[2] + pq[3];
  float mean = s * (1.0f/1024.0f);
  float var  = q * (1.0f/1024.0f) - mean*mean;
  float rstd = rsqrtf(var + 1e-5f);
  float4 gv = ((const float4*)g)[t];
  float4 bv = ((const float4*)b)[t];
  ushort4 o;
  o.x = f2bf((v.x - mean)*rstd*gv.x + bv.x);
  o.y = f2bf((v.y - mean)*rstd*gv.y + bv.y);
  o.z = f2bf((v.z - mean)*rstd*gv.z + bv.z);
  o.w = f2bf((v.w - mean)*rstd*gv.w + bv.w);
  ((ushort4*)(out + (size_t)row * 1024))[t] = o;
}

// ---------------------------------------------------------------------------
// GEMM 256x256 tile, BK=64, 512 threads (8 waves, 2M x 4N), 8-phase schedule.
// (frozen — validated R5-R11; used for MLP1)
// ---------------------------------------------------------------------------
#define MF(FRB, FCB) { \
  _Pragma("unroll") for (int ks = 0; ks < 2; ks++) \
  _Pragma("unroll") for (int fr = 0; fr < 4; fr++) \
  _Pragma("unroll") for (int fc = 0; fc < 2; fc++) \
    acc[(FRB)+fr][(FCB)+fc] = __builtin_amdgcn_mfma_f32_16x16x32_bf16( \
        a[fr][ks], b[fc][ks], acc[(FRB)+fr][(FCB)+fc], 0, 0, 0); }

#define STAGE(BUF, H, KT) { \
  async16(hbase[H] + (size_t)gr_[0]*K + (KT)*64 + gc_[0], &lds[BUF][H][t*8]); \
  async16(hbase[H] + (size_t)gr_[1]*K + (KT)*64 + gc_[1], &lds[BUF][H][4096 + t*8]); }

#define BARRIER() { __builtin_amdgcn_s_barrier(); __builtin_amdgcn_sched_barrier(0); }

#define STAGE_DECODE() \
  int gr_[2], gc_[2]; \
  _Pragma("unroll") \
  for (int i = 0; i < 2; i++){ \
    int ch = i*512 + t; \
    int sr = ch >> 7, sc = (ch >> 6) & 1, r = (ch >> 2) & 15; \
    int c  = ((ch & 3) * 8) ^ (((r >> 3) & 1) << 4); \
    gr_[i] = sr*16 + r; \
    gc_[i] = sc*32 + c; \
  }

#define EPILOG_STORE() { \
  float v = acc[fr][fc][r] + bb; \
  if constexpr (EPI == 2) \
    v = 0.5f * v * (1.0f + erff(v * 0.70710678118654752f)); \
  size_t idx = (size_t)(rowb + r) * N + col; \
  if constexpr (EPI == 1) \
    ((float*)Cp)[idx] = v + res[idx]; \
  else \
    ((u16*)Cp)[idx] = f2bf(v); }

template<int EPI>
__global__ __launch_bounds__(512, 2) void k_gemm256(const u16* __restrict__ A,
    const u16* __restrict__ Bw, const float* __restrict__ bias, void* __restrict__ Cp,
    const float* __restrict__ res, int M, int N, int K, int ntn){
  __shared__ __align__(16) u16 lds[2][4][8192];  // 128 KiB
  const int t = threadIdx.x;
  const int l = t & 63, w = t >> 6;
  const int wm = w >> 2, wn = w & 3;             // 2 x 4 wave grid
  const int lr = l & 15, g = l >> 4;

  const int nwg = gridDim.x;
  int wg = blockIdx.x;
  if (!(nwg & 7)) wg = (wg & 7) * (nwg >> 3) + (wg >> 3);   // XCD swizzle (T1)
  const int bm = (wg / ntn) * 256, bn = (wg % ntn) * 256;

  STAGE_DECODE();
  const u16* hbase[4] = { A  + (size_t) bm        * K,
                          A  + (size_t)(bm + 128) * K,
                          Bw + (size_t) bn        * K,
                          Bw + (size_t)(bn + 128) * K };

  const int roff = lr*32 + ((g*8) ^ (((lr >> 3) & 1) << 4));

  f32x4 acc[8][4];
  #pragma unroll
  for (int i = 0; i < 8; i++)
    #pragma unroll
    for (int j = 0; j < 4; j++)
      acc[i][j] = (f32x4)(0.0f);
  short8 a[4][2], b[2][2];

  #define LDA(HB) { _Pragma("unroll") for (int fr = 0; fr < 4; fr++) \
    _Pragma("unroll") for (int ks = 0; ks < 2; ks++) \
      a[fr][ks] = *(const short8*)((HB) + (fr*4 + wm*2 + ks)*512 + roff); }
  #define LDB(HB) { _Pragma("unroll") for (int fc = 0; fc < 2; fc++) \
    _Pragma("unroll") for (int ks = 0; ks < 2; ks++) \
      b[fc][ks] = *(const short8*)((HB) + ((fc*4 + wn)*2 + ks)*512 + roff); }

  const int NT = K >> 6;
  STAGE(0, 0, 0); STAGE(0, 2, 0); STAGE(0, 3, 0); STAGE(0, 1, 0);
  asm volatile("s_waitcnt vmcnt(4)" ::: "memory");   // A0,B0 landed
  BARRIER();

  for (int kt = 0; kt < NT; kt++){
    const int cu = kt & 1, nx = cu ^ 1;
    const u16* LA0 = lds[cu][0]; const u16* LA1 = lds[cu][1];
    const u16* LB0 = lds[cu][2]; const u16* LB1 = lds[cu][3];
    const bool pf = (kt + 1 < NT);
    // ---- P1: quadrant (A0, B0) ----
    LDA(LA0); LDB(LB0);
    if (pf) STAGE(nx, 0, kt+1);
    __builtin_amdgcn_s_setprio(1);
    MF(0, 0);
    __builtin_amdgcn_s_setprio(0);
    if (pf) asm volatile("s_waitcnt vmcnt(4)" ::: "memory");  // B1(kt) landed
    else    asm volatile("s_waitcnt vmcnt(2)" ::: "memory");
    BARRIER();
    // ---- P2: quadrant (A0, B1) ----
    LDB(LB1);
    if (pf) STAGE(nx, 2, kt+1);
    __builtin_amdgcn_s_setprio(1);
    MF(0, 2);
    __builtin_amdgcn_s_setprio(0);
    if (pf) asm volatile("s_waitcnt vmcnt(4)" ::: "memory");  // A1(kt) landed
    else    asm volatile("s_waitcnt vmcnt(0)" ::: "memory");
    BARRIER();
    // ---- P3: quadrant (A1, B1) ----
    LDA(LA1);
    if (pf) STAGE(nx, 3, kt+1);
    __builtin_amdgcn_s_setprio(1);
    MF(4, 2);
    __builtin_amdgcn_s_setprio(0);
    BARRIER();
    // ---- P4: quadrant (A1, B0) ----
    LDB(LB0);
    if (pf) STAGE(nx, 1, kt+1);
    __builtin_amdgcn_s_setprio(1);
    MF(4, 0);
    __builtin_amdgcn_s_setprio(0);
    if (pf) asm volatile("s_waitcnt vmcnt(4)" ::: "memory");  // A0,B0(kt+1) landed
    BARRIER();
  }

  const int m0 = bm + wm*16 + g*4;
  const int n0 = bn + wn*16 + lr;
  #pragma unroll
  for (int fc = 0; fc < 4; fc++){
    int col = n0 + fc*64;
    float bb = bias[col];
    #pragma unroll
    for (int fr = 0; fr < 8; fr++){
      int rowb = m0 + fr*32;
      #pragma unroll
      for (int r = 0; r < 4; r++) EPILOG_STORE();
    }
  }
  #undef LDA
  #undef LDB
}

// ---------------------------------------------------------------------------
// GEMM 128x256 tile, BK=64, 512 threads (8 waves, 2M x 4N), 2-phase/K-tile.
// (validated R8-R11; used for QKV / Wo / MLP2)
// ---------------------------------------------------------------------------
template<int EPI>
__global__ __launch_bounds__(512, 2) void k_gemm128(const u16* __restrict__ A,
    const u16* __restrict__ Bw, const float* __restrict__ bias, void* __restrict__ Cp,
    const float* __restrict__ res, int M, int N, int K, int ntn){
  __shared__ __align__(16) u16 lds[2][3][8192];  // 96 KiB
  const int t = threadIdx.x;
  const int l = t & 63, w = t >> 6;
  const int wm = w >> 2, wn = w & 3;             // 2 x 4 wave grid
  const int lr = l & 15, g = l >> 4;

  const int nwg = gridDim.x;
  int wg = blockIdx.x;
  if (!(nwg & 7)) wg = (wg & 7) * (nwg >> 3) + (wg >> 3);   // XCD swizzle (T1)
  const int bm = (wg / ntn) * 128, bn = (wg % ntn) * 256;

  STAGE_DECODE();
  const u16* hbase[3] = { A  + (size_t) bm        * K,
                          Bw + (size_t) bn        * K,
                          Bw + (size_t)(bn + 128) * K };

  const int roff = lr*32 + ((g*8) ^ (((lr >> 3) & 1) << 4));

  f32x4 acc[4][4];
  #pragma unroll
  for (int i = 0; i < 4; i++)
    #pragma unroll
    for (int j = 0; j < 4; j++)
      acc[i][j] = (f32x4)(0.0f);
  short8 a[4][2], b[2][2];

  #define LDA(HB) { _Pragma("unroll") for (int fr = 0; fr < 4; fr++) \
    _Pragma("unroll") for (int ks = 0; ks < 2; ks++) \
      a[fr][ks] = *(const short8*)((HB) + (fr*4 + wm*2 + ks)*512 + roff); }
  #define LDB(HB) { _Pragma("unroll") for (int fc = 0; fc < 2; fc++) \
    _Pragma("unroll") for (int ks = 0; ks < 2; ks++) \
      b[fc][ks] = *(const short8*)((HB) + ((fc*4 + wn)*2 + ks)*512 + roff); }
  #define MF128(FCB) { \
    _Pragma("unroll") for (int ks = 0; ks < 2; ks++) \
    _Pragma("unroll") for (int fr = 0; fr < 4; fr++) \
    _Pragma("unroll") for (int fc = 0; fc < 2; fc++) \
      acc[fr][(FCB)+fc] = __builtin_amdgcn_mfma_f32_16x16x32_bf16( \
          a[fr][ks], b[fc][ks], acc[fr][(FCB)+fc], 0, 0, 0); }

  const int NT = K >> 6;
  STAGE(0, 0, 0); STAGE(0, 1, 0); STAGE(0, 2, 0);
  asm volatile("s_waitcnt vmcnt(2)" ::: "memory");   // A,B0 landed
  BARRIER();

  for (int kt = 0; kt < NT; kt++){
    const int cu = kt & 1, nx = cu ^ 1;
    const bool pf = (kt + 1 < NT);
    // ---- P1: (A, B0) ----
    LDA(lds[cu][0]); LDB(lds[cu][1]);
    if (pf){ STAGE(nx, 0, kt+1); STAGE(nx, 1, kt+1); }
    __builtin_amdgcn_s_setprio(1);
    MF128(0);
    __builtin_amdgcn_s_setprio(0);
    if (pf) asm volatile("s_waitcnt vmcnt(4)" ::: "memory");  // B1(kt) landed
    else    asm volatile("s_waitcnt vmcnt(0)" ::: "memory");
    BARRIER();
    // ---- P2: (A, B1) ----
    LDB(lds[cu][2]);
    if (pf) STAGE(nx, 2, kt+1);
    __builtin_amdgcn_s_setprio(1);
    MF128(2);
    __builtin_amdgcn_s_setprio(0);
    if (pf) asm volatile("s_waitcnt vmcnt(2)" ::: "memory");  // A,B0(kt+1) landed
    BARRIER();
  }

  const int m0 = bm + wm*16 + g*4;
  const int n0 = bn + wn*16 + lr;
  #pragma unroll
  for (int fc = 0; fc < 4; fc++){
    int col = n0 + fc*64;
    float bb = bias[col];
    #pragma unroll
    for (int fr = 0; fr < 4; fr++){
      int rowb = m0 + fr*32;
      #pragma unroll
      for (int r = 0; r < 4; r++) EPILOG_STORE();
    }
  }
  #undef LDA
  #undef LDB
  #undef MF128
}
#undef MF
#undef STAGE
#undef BARRIER
#undef STAGE_DECODE
#undef EPILOG_STORE

// ---------------------------------------------------------------------------
// Flash attention fwd, swapped-QK^T 32x32, 512 threads / 8 waves, QBLK=256.
// T15 att[2] pipeline: QK^T(kt+1) issued into a second S-register set BEFORE
// softmax(kt) -> next-tile MFMA latency hides under current-tile VALU.
// K 3-buffered (2-deep prefetch), V double-buffered (unchanged path).
// Explicit 2-step unrolled loop with named saA/saB (no runtime reg indexing).
// grid = 512 (64 bh x 8 q-tiles), XCD-chunked remap. No setprio.
// ---------------------------------------------------------------------------
#define FSTEP(KK, SC0, SC1, SP0, SP1) { \
  const int cur = (KK) & 1; \
  /* phase 1a: issue K(kt+2) async -> lK[(kt+2)%3] */ \
  if ((KK) + 2 < 32){ \
    int row = t >> 3, c = (t & 7) ^ (row & 7); \
    async16(Kg + (size_t)(((KK)+2)*64 + row) * QSTR + c*8, \
            kbase + (size_t)(((KK)+2)%3)*4096 + t*8); \
  } \
  /* phase 1b: V(kt+1) -> regs */ \
  if ((KK) + 1 < 32){ \
    const u16* vs = Vg + (size_t)(((KK)+1)*64 + vkv0) * QSTR + vdh*4; \
    v0s = *(const short4v*)(vs); \
    v1s = *(const short4v*)(vs + QSTR); \
  } \
  /* phase 2a: QK^T(kt+1) -> SP (issued before softmax; overlaps on MFMA pipe) */ \
  if ((KK) + 1 < 32){ \
    const char* lKn = (const char*)(kbase + (size_t)(((KK)+1)%3)*4096); \
    SP0 = (f32x16)(0.0f); SP1 = (f32x16)(0.0f); \
    _Pragma("unroll") \
    for (int d0 = 0; d0 < 4; d0++){ \
      int cb = (d0*32 + 16*h) ^ rb; \
      short8 kf0 = *(const short8*)(lKn + c31*128 + cb); \
      short8 kf1 = *(const short8*)(lKn + (32+c31)*128 + cb); \
      SP0 = __builtin_amdgcn_mfma_f32_32x32x16_bf16(kf0, qf[d0], SP0, 0, 0, 0); \
      SP1 = __builtin_amdgcn_mfma_f32_32x32x16_bf16(kf1, qf[d0], SP1, 0, 0, 0); \
    } \
  } \
  /* phase 2b: online softmax on SC (tile kt), log2 domain */ \
  { \
    float pm = fmaxf(fmaxf(SC0[0], SC0[1]), SC0[2]); \
    _Pragma("unroll") \
    for (int r = 3; r < 15; r += 2) pm = fmaxf(fmaxf(pm, SC0[r]), SC0[r+1]); \
    pm = fmaxf(fmaxf(pm, SC0[15]), SC1[0]); \
    _Pragma("unroll") \
    for (int r = 1; r < 15; r += 2) pm = fmaxf(fmaxf(pm, SC1[r]), SC1[r+1]); \
    pm = fmaxf(pm, SC1[15]); \
    pm = fmaxf(pm, __shfl_xor(pm, 32)); \
    if (!__all(pm <= m_run + 8.0f)){ \
      float mnew = fmaxf(m_run, pm); \
      float alpha = fexp2(m_run - mnew); \
      m_run = mnew; \
      l_run *= alpha; \
      _Pragma("unroll") \
      for (int r = 0; r < 16; r++){ \
        int qr = (r&3) + 8*(r>>2) + 4*h; \
        float ar = __shfl(alpha, qr); \
        oa0[r] *= ar; oa1[r] *= ar; \
      } \
    } \
    float rs = 0.0f; \
    _Pragma("unroll") \
    for (int r = 0; r < 16; r++){ float p = fexp2(SC0[r] - m_run); SC0[r] = p; rs += p; } \
    _Pragma("unroll") \
    for (int r = 0; r < 16; r++){ float p = fexp2(SC1[r] - m_run); SC1[r] = p; rs += p; } \
    rs += __shfl_xor(rs, 32); \
    l_run += rs; \
  } \
  /* phase 2c: P -> A-frags (cvt_pk + permlane32_swap) */ \
  short8 pa[4]; \
  { \
    u32 a0 = cvt_pk_bf16(SC0[0], SC0[1]),  a1 = cvt_pk_bf16(SC0[2], SC0[3]); \
    u32 a2 = cvt_pk_bf16(SC0[4], SC0[5]),  a3 = cvt_pk_bf16(SC0[6], SC0[7]); \
    asm("v_permlane32_swap_b32 %0, %1" : "+v"(a0), "+v"(a2)); \
    asm("v_permlane32_swap_b32 %0, %1" : "+v"(a1), "+v"(a3)); \
    pa[0] = frag4(a0, a1, a2, a3); \
    u32 b0 = cvt_pk_bf16(SC0[8], SC0[9]),  b1 = cvt_pk_bf16(SC0[10], SC0[11]); \
    u32 b2 = cvt_pk_bf16(SC0[12], SC0[13]), b3 = cvt_pk_bf16(SC0[14], SC0[15]); \
    asm("v_permlane32_swap_b32 %0, %1" : "+v"(b0), "+v"(b2)); \
    asm("v_permlane32_swap_b32 %0, %1" : "+v"(b1), "+v"(b3)); \
    pa[1] = frag4(b0, b1, b2, b3); \
    u32 c0 = cvt_pk_bf16(SC1[0], SC1[1]),  c1 = cvt_pk_bf16(SC1[2], SC1[3]); \
    u32 c2 = cvt_pk_bf16(SC1[4], SC1[5]),  c3 = cvt_pk_bf16(SC1[6], SC1[7]); \
    asm("v_permlane32_swap_b32 %0, %1" : "+v"(c0), "+v"(c2)); \
    asm("v_permlane32_swap_b32 %0, %1" : "+v"(c1), "+v"(c3)); \
    pa[2] = frag4(c0, c1, c2, c3); \
    u32 d0 = cvt_pk_bf16(SC1[8], SC1[9]),  d1 = cvt_pk_bf16(SC1[10], SC1[11]); \
    u32 d2 = cvt_pk_bf16(SC1[12], SC1[13]), d3 = cvt_pk_bf16(SC1[14], SC1[15]); \
    asm("v_permlane32_swap_b32 %0, %1" : "+v"(d0), "+v"(d2)); \
    asm("v_permlane32_swap_b32 %0, %1" : "+v"(d1), "+v"(d3)); \
    pa[3] = frag4(d0, d1, d2, d3); \
  } \
  /* phase 2d: O += P V (tile kt) */ \
  { \
    const char* lVc = (const char*)&lVT[cur][0]; \
    _Pragma("unroll") \
    for (int ks = 0; ks < 4; ks++){ \
      int cb = (ks*32 + 16*h) ^ rb; \
      short8 vb0 = *(const short8*)(lVc + c31*128 + cb); \
      short8 vb1 = *(const short8*)(lVc + (32+c31)*128 + cb); \
      oa0 = __builtin_amdgcn_mfma_f32_32x32x16_bf16(pa[ks], vb0, oa0, 0, 0, 0); \
      oa1 = __builtin_amdgcn_mfma_f32_32x32x16_bf16(pa[ks], vb1, oa1, 0, 0, 0); \
    } \
  } \
  /* phase 3: write staged V(kt+1) into other V buffer */ \
  if ((KK) + 1 < 32){ \
    _Pragma("unroll") \
    for (int j = 0; j < 4; j++){ \
      int d = vdh*4 + j; \
      u32 word = (u32)(u16)v0s[j] | ((u32)(u16)v1s[j] << 16); \
      *(u32*)((char*)&lVT[cur^1][0] + d*128 + ((vkv0*2) ^ ((d&7)<<4))) = word; \
    } \
  } \
  __syncthreads(); }

__global__ __launch_bounds__(512, 4) void k_flash(const u16* __restrict__ QKV,
                                                  u16* __restrict__ O){
  constexpr int QSTR = 3072, OSTR = 1024;
  __shared__ __align__(16) u16 lK [3][64*64];   // [kv][d], chunk-XOR swizzle, 3-buf
  __shared__ __align__(16) u16 lVT[2][64*64];   // [d][kv], chunk-XOR swizzle

  const int t = threadIdx.x;
  const int l = t & 63, w = t >> 6;
  const int c31 = l & 31, h = l >> 5;
  const int bx = blockIdx.x;
  const int rbx = ((bx & 7) << 6) + (bx >> 3);      // XCD chunk map
  const int qt = rbx & 7, bh = rbx >> 3;            // bh = b*16 + head
  const size_t rowbase = (size_t)(bh >> 4) * 2048;  // batch row offset
  const int hd = (bh & 15) * 64;                    // head col offset
  const u16* Qg = QKV + rowbase * QSTR + hd;
  const u16* Kg = Qg + 1024;
  const u16* Vg = Qg + 2048;
  u16* Og = O + rowbase * OSTR + hd;
  const int qrow0 = qt * 256 + w * 32;
  u16* kbase = &lK[0][0];

  // ---- Q fragments (B-operand of swapped QK^T), pre-scaled 0.125*log2e ----
  short8 qf[4];
  #pragma unroll
  for (int d0 = 0; d0 < 4; d0++){
    short8 v = *(const short8*)(Qg + (size_t)(qrow0 + c31) * QSTR + d0*16 + 8*h);
    #pragma unroll
    for (int j = 0; j < 8; j++)
      v[j] = (short)f2bf(bf2f((u16)v[j]) * 0.18033688011112042f);
    qf[d0] = v;
  }

  f32x16 oa0 = (f32x16)(0.0f), oa1 = (f32x16)(0.0f);
  float m_run = -1e30f, l_run = 0.0f;

  const int vkv0 = 2*(t & 31), vdh = t >> 5;   // V: 32 kv-pairs x 16 d-chunks(4)
  const int rb = (c31 & 7) << 4;               // LDS chunk-XOR swizzle term

  // ---- prologue: stage K(0), K(1), V(0) ----
  {
    int row = t >> 3, c = (t & 7) ^ (row & 7);
    async16(Kg + (size_t)row * QSTR + c*8,        &lK[0][t*8]);
    async16(Kg + (size_t)(64 + row) * QSTR + c*8, &lK[1][t*8]);
    const u16* vs = Vg + (size_t)vkv0 * QSTR + vdh*4;
    short4v v0 = *(const short4v*)(vs);
    short4v v1 = *(const short4v*)(vs + QSTR);
    #pragma unroll
    for (int j = 0; j < 4; j++){
      int d = vdh*4 + j;
      u32 word = (u32)(u16)v0[j] | ((u32)(u16)v1[j] << 16);
      *(u32*)((char*)&lVT[0][0] + d*128 + ((vkv0*2) ^ ((d&7)<<4))) = word;
    }
  }
  __syncthreads();

  // ---- prologue QK^T(0) -> saA ----
  f32x16 saA0 = (f32x16)(0.0f), saA1 = (f32x16)(0.0f);
  f32x16 saB0, saB1;
  {
    const char* lKn = (const char*)&lK[0][0];
    #pragma unroll
    for (int d0 = 0; d0 < 4; d0++){
      int cb = (d0*32 + 16*h) ^ rb;
      short8 kf0 = *(const short8*)(lKn + c31*128 + cb);
      short8 kf1 = *(const short8*)(lKn + (32+c31)*128 + cb);
      saA0 = __builtin_amdgcn_mfma_f32_32x32x16_bf16(kf0, qf[d0], saA0, 0, 0, 0);
      saA1 = __builtin_amdgcn_mfma_f32_32x32x16_bf16(kf1, qf[d0], saA1, 0, 0, 0);
    }
  }

  short4v v0s, v1s;
  for (int kt = 0; kt < 32; kt += 2){
    FSTEP(kt,     saA0, saA1, saB0, saB1);
    FSTEP(kt + 1, saB0, saB1, saA0, saA1);
  }

  // ---- epilogue: normalize + store ----
  float linv = 1.0f / l_run;
  #pragma unroll
  for (int r = 0; r < 16; r++){
    int qr = (r&3) + 8*(r>>2) + 4*h;
    float lr2 = __shfl(linv, qr);
    size_t ro = (size_t)(qrow0 + qr) * OSTR;
    Og[ro + c31]      = f2bf(oa0[r] * lr2);
    Og[ro + 32 + c31] = f2bf(oa1[r] * lr2);
  }
}
#undef FSTEP

// ---------------------------------------------------------------------------
// launch
// ---------------------------------------------------------------------------
extern "C" void kernel_launch(void* const* d_in, const int* in_sizes, int n_in,
                              void* d_out, int out_size, void* d_ws, size_t ws_size,
                              hipStream_t stream){
  const float* x   = (const float*)d_in[0];
  const float* Wq  = (const float*)d_in[2];
  const float* bq  = (const float*)d_in[3];
  const float* Wk  = (const float*)d_in[4];
  const float* bk  = (const float*)d_in[5];
  const float* Wv  = (const float*)d_in[6];
  const float* bv  = (const float*)d_in[7];
  const float* Wo  = (const float*)d_in[8];
  const float* bo  = (const float*)d_in[9];
  const float* g1  = (const float*)d_in[10];
  const float* b1  = (const float*)d_in[11];
  const float* g2  = (const float*)d_in[12];
  const float* b2  = (const float*)d_in[13];
  const float* Wm1 = (const float*)d_in[14];
  const float* bm1 = (const float*)d_in[15];
  const float* Wm2 = (const float*)d_in[16];
  const float* bm2 = (const float*)d_in[17];

  const size_t MB = 1024 * 1024;
  char* ws = (char*)d_ws;
  u16*   wqkv = (u16*)(ws + 0*MB);     // 6 MB
  u16*   wo   = (u16*)(ws + 6*MB);     // 2 MB
  u16*   wm1  = (u16*)(ws + 8*MB);     // 8 MB
  u16*   wm2  = (u16*)(ws + 16*MB);    // 8 MB
  float* bqkv = (float*)(ws + 24*MB);  // 12 KB
  u16*   nrm  = (u16*)(ws + 25*MB);    // 16 MB (LN1 out, later LN2 out)
  u16*   qkvb = (u16*)(ws + 41*MB);    // 48 MB
  u16*   attn = (u16*)(ws + 89*MB);    // 16 MB
  float* x2   = (float*)(ws + 105*MB); // 32 MB  (total 137 MB)
  u16*   h1   = (u16*)(ws + 41*MB);    // reuse qkvb+attn (64 MB) after attn

  // fused: weight convert + bias concat + LN1 (independent work, one launch)
  k_prep<<<20483, 256, 0, stream>>>(Wq, Wk, Wv, Wo, Wm1, Wm2, bq, bk, bv,
                                    wqkv, wo, wm1, wm2, bqkv, x, g1, b1, nrm);

  const int M = 8192;
  // fused QKV projection (BM=128: grid 768, no tail)
  k_gemm128<0><<<dim3(64*12), 512, 0, stream>>>(nrm, wqkv, bqkv, qkvb, nullptr, M, 3072, 1024, 12);
  // attention (512 threads, QBLK=256, T15 pipelined)
  k_flash<<<512, 512, 0, stream>>>(qkvb, attn);
  // out proj + residual (BM=128: grid 256 = full chip)
  k_gemm128<1><<<dim3(64*4), 512, 0, stream>>>(attn, wo, bo, x2, x, M, 1024, 1024, 4);
  // LN2
  k_ln<<<M, 256, 0, stream>>>(x2, g2, b2, nrm);
  // MLP1: h1 = gelu(nrm @ Wm1^T + bm1)
  k_gemm256<2><<<dim3(32*16), 512, 0, stream>>>(nrm, wm1, bm1, h1, nullptr, M, 4096, 1024, 16);
  // MLP2: out = x2 + h1 @ Wm2^T + bm2  (BM=128: grid 256 = full chip)
  k_gemm128<1><<<dim3(64*4), 512, 0, stream>>>(h1, wm2, bm2, d_out, x2, M, 1024, 4096, 4);
}

// Round 13
// 383.475 us; speedup vs baseline: 1.3289x; 1.3289x over previous
//
#include <hip/hip_runtime.h>
#include <math.h>

// ---------------------------------------------------------------------------
// Transformer encoder block, bf16 MFMA compute, fp32 I/O.
// B=4 S=2048 H=1024 NH=16 HD=64 FF=4096
// ---------------------------------------------------------------------------

typedef unsigned short u16;
typedef unsigned int   u32;
typedef __attribute__((ext_vector_type(4)))  float f32x4;
typedef __attribute__((ext_vector_type(16))) float f32x16;
typedef __attribute__((ext_vector_type(8)))  short short8;
typedef __attribute__((ext_vector_type(4)))  short short4v;

__device__ __forceinline__ u16 f2bf(float f){
  union { float f; u32 u; } v; v.f = f;
  u32 u = v.u;
  return (u16)((u + 0x7fffu + ((u >> 16) & 1u)) >> 16);   // RNE
}
__device__ __forceinline__ float bf2f(u16 h){
  union { u32 u; float f; } v; v.u = ((u32)h) << 16;
  return v.f;
}

__device__ __forceinline__ void async16(const u16* g, u16* l){
  __builtin_amdgcn_global_load_lds((const __attribute__((address_space(1))) u32*)g,
                                   (__attribute__((address_space(3))) u32*)l, 16, 0, 0);
}

__device__ __forceinline__ u32 cvt_pk_bf16(float lo, float hi){
  u32 r;
  asm("v_cvt_pk_bf16_f32 %0, %1, %2" : "=v"(r) : "v"(lo), "v"(hi));
  return r;
}

__device__ __forceinline__ float fexp2(float x){   // native 2^x, guaranteed
  float r;
  asm("v_exp_f32 %0, %1" : "=v"(r) : "v"(x));
  return r;
}

__device__ __forceinline__ short8 frag4(u32 a, u32 b, u32 c, u32 d){
  union { u32 u[4]; short8 s; } x;
  x.u[0] = a; x.u[1] = b; x.u[2] = c; x.u[3] = d;
  return x.s;
}

// ---------------------------------------------------------------------------
// prep: fused weight fp32->bf16 convert + bias concat + LayerNorm1.
// blocks [0, 12291): convert chunks; blocks [12291, 20483): LN1 rows.
// ---------------------------------------------------------------------------
__global__ __launch_bounds__(256) void k_prep(
    const float* __restrict__ Wq, const float* __restrict__ Wk,
    const float* __restrict__ Wv, const float* __restrict__ Wo,
    const float* __restrict__ Wm1, const float* __restrict__ Wm2,
    const float* __restrict__ bq, const float* __restrict__ bk,
    const float* __restrict__ bv,
    u16* __restrict__ wqkv, u16* __restrict__ wo,
    u16* __restrict__ wm1, u16* __restrict__ wm2, float* __restrict__ bqkv,
    const float* __restrict__ x, const float* __restrict__ g1,
    const float* __restrict__ b1, u16* __restrict__ nrm){
  __shared__ float ps[4], pq[4];
  const int t = threadIdx.x;
  if (blockIdx.x >= 12291){
    // ---- LN1 row ----
    int row = blockIdx.x - 12291;
    const float* xr = x + (size_t)row * 1024;
    float4 v = ((const float4*)xr)[t];
    float s = v.x + v.y + v.z + v.w;
    float q = v.x*v.x + v.y*v.y + v.z*v.z + v.w*v.w;
    #pragma unroll
    for (int off = 1; off < 64; off <<= 1){
      s += __shfl_xor(s, off);
      q += __shfl_xor(q, off);
    }
    int w = t >> 6, l = t & 63;
    if (l == 0){ ps[w] = s; pq[w] = q; }
    __syncthreads();
    s = ps[0] + ps[1] + ps[2] + ps[3];
    q = pq[0] + pq[1] + pq[2] + pq[3];
    float mean = s * (1.0f/1024.0f);
    float var  = q * (1.0f/1024.0f) - mean*mean;
    float rstd = rsqrtf(var + 1e-5f);
    float4 gv = ((const float4*)g1)[t];
    float4 bv4 = ((const float4*)b1)[t];
    ushort4 o;
    o.x = f2bf((v.x - mean)*rstd*gv.x + bv4.x);
    o.y = f2bf((v.y - mean)*rstd*gv.y + bv4.y);
    o.z = f2bf((v.z - mean)*rstd*gv.z + bv4.z);
    o.w = f2bf((v.w - mean)*rstd*gv.w + bv4.w);
    ((ushort4*)(nrm + (size_t)row * 1024))[t] = o;
    return;
  }
  // ---- weight convert ----
  int c = blockIdx.x * 256 + t;
  const float* src; u16* dst;
  if      (c <  262144){ src = Wq  + c*4;             dst = wqkv + c*4; }
  else if (c <  524288){ src = Wk  + (c-262144)*4;    dst = wqkv + 1048576 + (c-262144)*4; }
  else if (c <  786432){ src = Wv  + (c-524288)*4;    dst = wqkv + 2097152 + (c-524288)*4; }
  else if (c < 1048576){ src = Wo  + (c-786432)*4;    dst = wo  + (c-786432)*4; }
  else if (c < 2097152){ src = Wm1 + (c-1048576)*4;   dst = wm1 + (c-1048576)*4; }
  else if (c < 3145728){ src = Wm2 + (c-2097152)*4;   dst = wm2 + (c-2097152)*4; }
  else if (c < 3146496){
    int i = (c - 3145728)*4;
    const float* bsrc = i < 1024 ? bq + i : (i < 2048 ? bk + i - 1024 : bv + i - 2048);
    *(float4*)(bqkv + i) = *(const float4*)bsrc;
    return;
  } else return;
  float4 v = *(const float4*)src;
  ushort4 o; o.x = f2bf(v.x); o.y = f2bf(v.y); o.z = f2bf(v.z); o.w = f2bf(v.w);
  *(ushort4*)dst = o;
}

// ---------------------------------------------------------------------------
// LayerNorm: fp32 [rows][1024] -> bf16 [rows][1024]. one block per row. (LN2)
// ---------------------------------------------------------------------------
__global__ __launch_bounds__(256) void k_ln(const float* __restrict__ x,
                                            const float* __restrict__ g,
                                            const float* __restrict__ b,
                                            u16* __restrict__ out){
  int row = blockIdx.x;
  int t = threadIdx.x;
  const float* xr = x + (size_t)row * 1024;
  float4 v = ((const float4*)xr)[t];
  float s = v.x + v.y + v.z + v.w;
  float q = v.x*v.x + v.y*v.y + v.z*v.z + v.w*v.w;
  #pragma unroll
  for (int off = 1; off < 64; off <<= 1){
    s += __shfl_xor(s, off);
    q += __shfl_xor(q, off);
  }
  __shared__ float ps[4], pq[4];
  int w = t >> 6, l = t & 63;
  if (l == 0){ ps[w] = s; pq[w] = q; }
  __syncthreads();
  s = ps[0] + ps[1] + ps[2] + ps[3];
  q = pq[0] + pq[1] + pq[2] + pq[3];
  float mean = s * (1.0f/1024.0f);
  float var  = q * (1.0f/1024.0f) - mean*mean;
  float rstd = rsqrtf(var + 1e-5f);
  float4 gv = ((const float4*)g)[t];
  float4 bv = ((const float4*)b)[t];
  ushort4 o;
  o.x = f2bf((v.x - mean)*rstd*gv.x + bv.x);
  o.y = f2bf((v.y - mean)*rstd*gv.y + bv.y);
  o.z = f2bf((v.z - mean)*rstd*gv.z + bv.z);
  o.w = f2bf((v.w - mean)*rstd*gv.w + bv.w);
  ((ushort4*)(out + (size_t)row * 1024))[t] = o;
}

// ---------------------------------------------------------------------------
// GEMM 256x256 tile, BK=64, 512 threads (8 waves, 2M x 4N), 8-phase schedule.
// (frozen — validated R5-R11; used for MLP1)
// ---------------------------------------------------------------------------
#define MF(FRB, FCB) { \
  _Pragma("unroll") for (int ks = 0; ks < 2; ks++) \
  _Pragma("unroll") for (int fr = 0; fr < 4; fr++) \
  _Pragma("unroll") for (int fc = 0; fc < 2; fc++) \
    acc[(FRB)+fr][(FCB)+fc] = __builtin_amdgcn_mfma_f32_16x16x32_bf16( \
        a[fr][ks], b[fc][ks], acc[(FRB)+fr][(FCB)+fc], 0, 0, 0); }

#define STAGE(BUF, H, KT) { \
  async16(hbase[H] + (size_t)gr_[0]*K + (KT)*64 + gc_[0], &lds[BUF][H][t*8]); \
  async16(hbase[H] + (size_t)gr_[1]*K + (KT)*64 + gc_[1], &lds[BUF][H][4096 + t*8]); }

#define BARRIER() { __builtin_amdgcn_s_barrier(); __builtin_amdgcn_sched_barrier(0); }

#define STAGE_DECODE() \
  int gr_[2], gc_[2]; \
  _Pragma("unroll") \
  for (int i = 0; i < 2; i++){ \
    int ch = i*512 + t; \
    int sr = ch >> 7, sc = (ch >> 6) & 1, r = (ch >> 2) & 15; \
    int c  = ((ch & 3) * 8) ^ (((r >> 3) & 1) << 4); \
    gr_[i] = sr*16 + r; \
    gc_[i] = sc*32 + c; \
  }

#define EPILOG_STORE() { \
  float v = acc[fr][fc][r] + bb; \
  if constexpr (EPI == 2) \
    v = 0.5f * v * (1.0f + erff(v * 0.70710678118654752f)); \
  size_t idx = (size_t)(rowb + r) * N + col; \
  if constexpr (EPI == 1) \
    ((float*)Cp)[idx] = v + res[idx]; \
  else \
    ((u16*)Cp)[idx] = f2bf(v); }

template<int EPI>
__global__ __launch_bounds__(512, 2) void k_gemm256(const u16* __restrict__ A,
    const u16* __restrict__ Bw, const float* __restrict__ bias, void* __restrict__ Cp,
    const float* __restrict__ res, int M, int N, int K, int ntn){
  __shared__ __align__(16) u16 lds[2][4][8192];  // 128 KiB
  const int t = threadIdx.x;
  const int l = t & 63, w = t >> 6;
  const int wm = w >> 2, wn = w & 3;             // 2 x 4 wave grid
  const int lr = l & 15, g = l >> 4;

  const int nwg = gridDim.x;
  int wg = blockIdx.x;
  if (!(nwg & 7)) wg = (wg & 7) * (nwg >> 3) + (wg >> 3);   // XCD swizzle (T1)
  const int bm = (wg / ntn) * 256, bn = (wg % ntn) * 256;

  STAGE_DECODE();
  const u16* hbase[4] = { A  + (size_t) bm        * K,
                          A  + (size_t)(bm + 128) * K,
                          Bw + (size_t) bn        * K,
                          Bw + (size_t)(bn + 128) * K };

  const int roff = lr*32 + ((g*8) ^ (((lr >> 3) & 1) << 4));

  f32x4 acc[8][4];
  #pragma unroll
  for (int i = 0; i < 8; i++)
    #pragma unroll
    for (int j = 0; j < 4; j++)
      acc[i][j] = (f32x4)(0.0f);
  short8 a[4][2], b[2][2];

  #define LDA(HB) { _Pragma("unroll") for (int fr = 0; fr < 4; fr++) \
    _Pragma("unroll") for (int ks = 0; ks < 2; ks++) \
      a[fr][ks] = *(const short8*)((HB) + (fr*4 + wm*2 + ks)*512 + roff); }
  #define LDB(HB) { _Pragma("unroll") for (int fc = 0; fc < 2; fc++) \
    _Pragma("unroll") for (int ks = 0; ks < 2; ks++) \
      b[fc][ks] = *(const short8*)((HB) + ((fc*4 + wn)*2 + ks)*512 + roff); }

  const int NT = K >> 6;
  STAGE(0, 0, 0); STAGE(0, 2, 0); STAGE(0, 3, 0); STAGE(0, 1, 0);
  asm volatile("s_waitcnt vmcnt(4)" ::: "memory");   // A0,B0 landed
  BARRIER();

  for (int kt = 0; kt < NT; kt++){
    const int cu = kt & 1, nx = cu ^ 1;
    const u16* LA0 = lds[cu][0]; const u16* LA1 = lds[cu][1];
    const u16* LB0 = lds[cu][2]; const u16* LB1 = lds[cu][3];
    const bool pf = (kt + 1 < NT);
    // ---- P1: quadrant (A0, B0) ----
    LDA(LA0); LDB(LB0);
    if (pf) STAGE(nx, 0, kt+1);
    __builtin_amdgcn_s_setprio(1);
    MF(0, 0);
    __builtin_amdgcn_s_setprio(0);
    if (pf) asm volatile("s_waitcnt vmcnt(4)" ::: "memory");  // B1(kt) landed
    else    asm volatile("s_waitcnt vmcnt(2)" ::: "memory");
    BARRIER();
    // ---- P2: quadrant (A0, B1) ----
    LDB(LB1);
    if (pf) STAGE(nx, 2, kt+1);
    __builtin_amdgcn_s_setprio(1);
    MF(0, 2);
    __builtin_amdgcn_s_setprio(0);
    if (pf) asm volatile("s_waitcnt vmcnt(4)" ::: "memory");  // A1(kt) landed
    else    asm volatile("s_waitcnt vmcnt(0)" ::: "memory");
    BARRIER();
    // ---- P3: quadrant (A1, B1) ----
    LDA(LA1);
    if (pf) STAGE(nx, 3, kt+1);
    __builtin_amdgcn_s_setprio(1);
    MF(4, 2);
    __builtin_amdgcn_s_setprio(0);
    BARRIER();
    // ---- P4: quadrant (A1, B0) ----
    LDB(LB0);
    if (pf) STAGE(nx, 1, kt+1);
    __builtin_amdgcn_s_setprio(1);
    MF(4, 0);
    __builtin_amdgcn_s_setprio(0);
    if (pf) asm volatile("s_waitcnt vmcnt(4)" ::: "memory");  // A0,B0(kt+1) landed
    BARRIER();
  }

  const int m0 = bm + wm*16 + g*4;
  const int n0 = bn + wn*16 + lr;
  #pragma unroll
  for (int fc = 0; fc < 4; fc++){
    int col = n0 + fc*64;
    float bb = bias[col];
    #pragma unroll
    for (int fr = 0; fr < 8; fr++){
      int rowb = m0 + fr*32;
      #pragma unroll
      for (int r = 0; r < 4; r++) EPILOG_STORE();
    }
  }
  #undef LDA
  #undef LDB
}

// ---------------------------------------------------------------------------
// GEMM 128x256 tile, BK=64, 512 threads (8 waves, 2M x 4N), 2-phase/K-tile.
// (validated R8-R11; used for QKV / Wo / MLP2)
// ---------------------------------------------------------------------------
template<int EPI>
__global__ __launch_bounds__(512, 2) void k_gemm128(const u16* __restrict__ A,
    const u16* __restrict__ Bw, const float* __restrict__ bias, void* __restrict__ Cp,
    const float* __restrict__ res, int M, int N, int K, int ntn){
  __shared__ __align__(16) u16 lds[2][3][8192];  // 96 KiB
  const int t = threadIdx.x;
  const int l = t & 63, w = t >> 6;
  const int wm = w >> 2, wn = w & 3;             // 2 x 4 wave grid
  const int lr = l & 15, g = l >> 4;

  const int nwg = gridDim.x;
  int wg = blockIdx.x;
  if (!(nwg & 7)) wg = (wg & 7) * (nwg >> 3) + (wg >> 3);   // XCD swizzle (T1)
  const int bm = (wg / ntn) * 128, bn = (wg % ntn) * 256;

  STAGE_DECODE();
  const u16* hbase[3] = { A  + (size_t) bm        * K,
                          Bw + (size_t) bn        * K,
                          Bw + (size_t)(bn + 128) * K };

  const int roff = lr*32 + ((g*8) ^ (((lr >> 3) & 1) << 4));

  f32x4 acc[4][4];
  #pragma unroll
  for (int i = 0; i < 4; i++)
    #pragma unroll
    for (int j = 0; j < 4; j++)
      acc[i][j] = (f32x4)(0.0f);
  short8 a[4][2], b[2][2];

  #define LDA(HB) { _Pragma("unroll") for (int fr = 0; fr < 4; fr++) \
    _Pragma("unroll") for (int ks = 0; ks < 2; ks++) \
      a[fr][ks] = *(const short8*)((HB) + (fr*4 + wm*2 + ks)*512 + roff); }
  #define LDB(HB) { _Pragma("unroll") for (int fc = 0; fc < 2; fc++) \
    _Pragma("unroll") for (int ks = 0; ks < 2; ks++) \
      b[fc][ks] = *(const short8*)((HB) + ((fc*4 + wn)*2 + ks)*512 + roff); }
  #define MF128(FCB) { \
    _Pragma("unroll") for (int ks = 0; ks < 2; ks++) \
    _Pragma("unroll") for (int fr = 0; fr < 4; fr++) \
    _Pragma("unroll") for (int fc = 0; fc < 2; fc++) \
      acc[fr][(FCB)+fc] = __builtin_amdgcn_mfma_f32_16x16x32_bf16( \
          a[fr][ks], b[fc][ks], acc[fr][(FCB)+fc], 0, 0, 0); }

  const int NT = K >> 6;
  STAGE(0, 0, 0); STAGE(0, 1, 0); STAGE(0, 2, 0);
  asm volatile("s_waitcnt vmcnt(2)" ::: "memory");   // A,B0 landed
  BARRIER();

  for (int kt = 0; kt < NT; kt++){
    const int cu = kt & 1, nx = cu ^ 1;
    const bool pf = (kt + 1 < NT);
    // ---- P1: (A, B0) ----
    LDA(lds[cu][0]); LDB(lds[cu][1]);
    if (pf){ STAGE(nx, 0, kt+1); STAGE(nx, 1, kt+1); }
    __builtin_amdgcn_s_setprio(1);
    MF128(0);
    __builtin_amdgcn_s_setprio(0);
    if (pf) asm volatile("s_waitcnt vmcnt(4)" ::: "memory");  // B1(kt) landed
    else    asm volatile("s_waitcnt vmcnt(0)" ::: "memory");
    BARRIER();
    // ---- P2: (A, B1) ----
    LDB(lds[cu][2]);
    if (pf) STAGE(nx, 2, kt+1);
    __builtin_amdgcn_s_setprio(1);
    MF128(2);
    __builtin_amdgcn_s_setprio(0);
    if (pf) asm volatile("s_waitcnt vmcnt(2)" ::: "memory");  // A,B0(kt+1) landed
    BARRIER();
  }

  const int m0 = bm + wm*16 + g*4;
  const int n0 = bn + wn*16 + lr;
  #pragma unroll
  for (int fc = 0; fc < 4; fc++){
    int col = n0 + fc*64;
    float bb = bias[col];
    #pragma unroll
    for (int fr = 0; fr < 4; fr++){
      int rowb = m0 + fr*32;
      #pragma unroll
      for (int r = 0; r < 4; r++) EPILOG_STORE();
    }
  }
  #undef LDA
  #undef LDB
  #undef MF128
}
#undef MF
#undef STAGE
#undef BARRIER
#undef STAGE_DECODE
#undef EPILOG_STORE

// ---------------------------------------------------------------------------
// Flash attention fwd, swapped-QK^T 32x32, 512 threads / 8 waves, QBLK=256.
// (R11-validated, 119.7 us — restored after R12's T15 spill regression)
// grid = 512 (64 bh x 8 q-tiles), XCD-chunked remap (8 heads/XCD -> KV in L2).
// No setprio (lockstep waves). Native v_exp_f32 softmax. v_max3 row-max.
// K via global_load_lds (inverse-swizzled source); V reg-staged, packed to
// V^T LDS (4 words/thread at 512 threads).
// ---------------------------------------------------------------------------
__global__ __launch_bounds__(512, 2) void k_flash(const u16* __restrict__ QKV,
                                                  u16* __restrict__ O){
  constexpr int QSTR = 3072, OSTR = 1024;
  __shared__ __align__(16) u16 lK [2][64*64];   // [kv][d], chunk-XOR swizzle
  __shared__ __align__(16) u16 lVT[2][64*64];   // [d][kv], chunk-XOR swizzle

  const int t = threadIdx.x;
  const int l = t & 63, w = t >> 6;
  const int c31 = l & 31, h = l >> 5;
  const int bx = blockIdx.x;
  const int rbx = ((bx & 7) << 6) + (bx >> 3);      // XCD chunk map
  const int qt = rbx & 7, bh = rbx >> 3;            // bh = b*16 + head
  const size_t rowbase = (size_t)(bh >> 4) * 2048;  // batch row offset
  const int hd = (bh & 15) * 64;                    // head col offset
  const u16* Qg = QKV + rowbase * QSTR + hd;
  const u16* Kg = Qg + 1024;
  const u16* Vg = Qg + 2048;
  u16* Og = O + rowbase * OSTR + hd;
  const int qrow0 = qt * 256 + w * 32;

  // ---- Q fragments (B-operand of swapped QK^T), pre-scaled 0.125*log2e ----
  short8 qf[4];
  #pragma unroll
  for (int d0 = 0; d0 < 4; d0++){
    short8 v = *(const short8*)(Qg + (size_t)(qrow0 + c31) * QSTR + d0*16 + 8*h);
    #pragma unroll
    for (int j = 0; j < 8; j++)
      v[j] = (short)f2bf(bf2f((u16)v[j]) * 0.18033688011112042f);
    qf[d0] = v;
  }

  f32x16 oa0 = (f32x16)(0.0f), oa1 = (f32x16)(0.0f);
  float m_run = -1e30f, l_run = 0.0f;

  const int vkv0 = 2*(t & 31), vdh = t >> 5;   // V: 32 kv-pairs x 16 d-chunks(4)
  const int rb = (c31 & 7) << 4;               // LDS chunk-XOR swizzle term

  // ---- prologue: stage tile 0 ----
  {
    int row = t >> 3, c = (t & 7) ^ (row & 7);
    async16(Kg + (size_t)row * QSTR + c*8, &lK[0][t*8]);
    const u16* vs = Vg + (size_t)vkv0 * QSTR + vdh*4;
    short4v v0 = *(const short4v*)(vs);
    short4v v1 = *(const short4v*)(vs + QSTR);
    #pragma unroll
    for (int j = 0; j < 4; j++){
      int d = vdh*4 + j;
      u32 word = (u32)(u16)v0[j] | ((u32)(u16)v1[j] << 16);
      *(u32*)((char*)&lVT[0][0] + d*128 + ((vkv0*2) ^ ((d&7)<<4))) = word;
    }
  }
  __syncthreads();

  short4v v0s, v1s;
  for (int kt = 0; kt < 32; kt++){
    const int cur = kt & 1;
    const char* lKc = (const char*)&lK[cur][0];
    const char* lVc = (const char*)&lVT[cur][0];

    // ---- phase 1: issue next-tile loads (K async -> LDS, V -> regs) ----
    if (kt < 31){
      int row = t >> 3, c = (t & 7) ^ (row & 7);
      async16(Kg + (size_t)((kt+1)*64 + row) * QSTR + c*8, &lK[cur^1][t*8]);
      const u16* vs = Vg + (size_t)((kt+1)*64 + vkv0) * QSTR + vdh*4;
      v0s = *(const short4v*)(vs);
      v1s = *(const short4v*)(vs + QSTR);
    }

    // ---- phase 2a: S^T = K Q^T  (2 kv-halves x 4 k-steps) ----
    f32x16 sa0 = (f32x16)(0.0f), sa1 = (f32x16)(0.0f);
    #pragma unroll
    for (int d0 = 0; d0 < 4; d0++){
      int cb = (d0*32 + 16*h) ^ rb;
      short8 kf0 = *(const short8*)(lKc + c31*128 + cb);
      short8 kf1 = *(const short8*)(lKc + (32+c31)*128 + cb);
      sa0 = __builtin_amdgcn_mfma_f32_32x32x16_bf16(kf0, qf[d0], sa0, 0, 0, 0);
      sa1 = __builtin_amdgcn_mfma_f32_32x32x16_bf16(kf1, qf[d0], sa1, 0, 0, 0);
    }

    // ---- phase 2b: online softmax (log2 domain), lane-local row ----
    float pm = fmaxf(fmaxf(sa0[0], sa0[1]), sa0[2]);
    #pragma unroll
    for (int r = 3; r < 15; r += 2) pm = fmaxf(fmaxf(pm, sa0[r]), sa0[r+1]);
    pm = fmaxf(fmaxf(pm, sa0[15]), sa1[0]);
    #pragma unroll
    for (int r = 1; r < 15; r += 2) pm = fmaxf(fmaxf(pm, sa1[r]), sa1[r+1]);
    pm = fmaxf(pm, sa1[15]);
    pm = fmaxf(pm, __shfl_xor(pm, 32));
    if (!__all(pm <= m_run + 8.0f)){        // defer-max (T13): p <= 2^8
      float mnew = fmaxf(m_run, pm);
      float alpha = fexp2(m_run - mnew);
      m_run = mnew;
      l_run *= alpha;
      #pragma unroll
      for (int r = 0; r < 16; r++){
        int qr = (r&3) + 8*(r>>2) + 4*h;
        float ar = __shfl(alpha, qr);
        oa0[r] *= ar; oa1[r] *= ar;
      }
    }
    float rs = 0.0f;
    #pragma unroll
    for (int r = 0; r < 16; r++){ float p = fexp2(sa0[r] - m_run); sa0[r] = p; rs += p; }
    #pragma unroll
    for (int r = 0; r < 16; r++){ float p = fexp2(sa1[r] - m_run); sa1[r] = p; rs += p; }
    rs += __shfl_xor(rs, 32);
    l_run += rs;

    // ---- phase 2c: P -> A-frags (cvt_pk + permlane32_swap, T12) ----
    short8 pa[4];
    {
      u32 a0 = cvt_pk_bf16(sa0[0], sa0[1]),  a1 = cvt_pk_bf16(sa0[2], sa0[3]);
      u32 a2 = cvt_pk_bf16(sa0[4], sa0[5]),  a3 = cvt_pk_bf16(sa0[6], sa0[7]);
      asm("v_permlane32_swap_b32 %0, %1" : "+v"(a0), "+v"(a2));
      asm("v_permlane32_swap_b32 %0, %1" : "+v"(a1), "+v"(a3));
      pa[0] = frag4(a0, a1, a2, a3);
      u32 b0 = cvt_pk_bf16(sa0[8], sa0[9]),  b1 = cvt_pk_bf16(sa0[10], sa0[11]);
      u32 b2 = cvt_pk_bf16(sa0[12], sa0[13]), b3 = cvt_pk_bf16(sa0[14], sa0[15]);
      asm("v_permlane32_swap_b32 %0, %1" : "+v"(b0), "+v"(b2));
      asm("v_permlane32_swap_b32 %0, %1" : "+v"(b1), "+v"(b3));
      pa[1] = frag4(b0, b1, b2, b3);
      u32 c0 = cvt_pk_bf16(sa1[0], sa1[1]),  c1 = cvt_pk_bf16(sa1[2], sa1[3]);
      u32 c2 = cvt_pk_bf16(sa1[4], sa1[5]),  c3 = cvt_pk_bf16(sa1[6], sa1[7]);
      asm("v_permlane32_swap_b32 %0, %1" : "+v"(c0), "+v"(c2));
      asm("v_permlane32_swap_b32 %0, %1" : "+v"(c1), "+v"(c3));
      pa[2] = frag4(c0, c1, c2, c3);
      u32 d0 = cvt_pk_bf16(sa1[8], sa1[9]),  d1 = cvt_pk_bf16(sa1[10], sa1[11]);
      u32 d2 = cvt_pk_bf16(sa1[12], sa1[13]), d3 = cvt_pk_bf16(sa1[14], sa1[15]);
      asm("v_permlane32_swap_b32 %0, %1" : "+v"(d0), "+v"(d2));
      asm("v_permlane32_swap_b32 %0, %1" : "+v"(d1), "+v"(d3));
      pa[3] = frag4(d0, d1, d2, d3);
    }

    // ---- phase 2d: O += P V  (4 kv-steps x 2 d-halves) ----
    #pragma unroll
    for (int ks = 0; ks < 4; ks++){
      int cb = (ks*32 + 16*h) ^ rb;
      short8 vb0 = *(const short8*)(lVc + c31*128 + cb);
      short8 vb1 = *(const short8*)(lVc + (32+c31)*128 + cb);
      oa0 = __builtin_amdgcn_mfma_f32_32x32x16_bf16(pa[ks], vb0, oa0, 0, 0, 0);
      oa1 = __builtin_amdgcn_mfma_f32_32x32x16_bf16(pa[ks], vb1, oa1, 0, 0, 0);
    }

    // ---- phase 3: write staged V^T into next buffer ----
    if (kt < 31){
      #pragma unroll
      for (int j = 0; j < 4; j++){
        int d = vdh*4 + j;
        u32 word = (u32)(u16)v0s[j] | ((u32)(u16)v1s[j] << 16);
        *(u32*)((char*)&lVT[cur^1][0] + d*128 + ((vkv0*2) ^ ((d&7)<<4))) = word;
      }
    }
    __syncthreads();
  }

  // ---- epilogue: normalize + store ----
  float linv = 1.0f / l_run;
  #pragma unroll
  for (int r = 0; r < 16; r++){
    int qr = (r&3) + 8*(r>>2) + 4*h;
    float lr2 = __shfl(linv, qr);
    size_t ro = (size_t)(qrow0 + qr) * OSTR;
    Og[ro + c31]      = f2bf(oa0[r] * lr2);
    Og[ro + 32 + c31] = f2bf(oa1[r] * lr2);
  }
}

// ---------------------------------------------------------------------------
// launch
// ---------------------------------------------------------------------------
extern "C" void kernel_launch(void* const* d_in, const int* in_sizes, int n_in,
                              void* d_out, int out_size, void* d_ws, size_t ws_size,
                              hipStream_t stream){
  const float* x   = (const float*)d_in[0];
  const float* Wq  = (const float*)d_in[2];
  const float* bq  = (const float*)d_in[3];
  const float* Wk  = (const float*)d_in[4];
  const float* bk  = (const float*)d_in[5];
  const float* Wv  = (const float*)d_in[6];
  const float* bv  = (const float*)d_in[7];
  const float* Wo  = (const float*)d_in[8];
  const float* bo  = (const float*)d_in[9];
  const float* g1  = (const float*)d_in[10];
  const float* b1  = (const float*)d_in[11];
  const float* g2  = (const float*)d_in[12];
  const float* b2  = (const float*)d_in[13];
  const float* Wm1 = (const float*)d_in[14];
  const float* bm1 = (const float*)d_in[15];
  const float* Wm2 = (const float*)d_in[16];
  const float* bm2 = (const float*)d_in[17];

  const size_t MB = 1024 * 1024;
  char* ws = (char*)d_ws;
  u16*   wqkv = (u16*)(ws + 0*MB);     // 6 MB
  u16*   wo   = (u16*)(ws + 6*MB);     // 2 MB
  u16*   wm1  = (u16*)(ws + 8*MB);     // 8 MB
  u16*   wm2  = (u16*)(ws + 16*MB);    // 8 MB
  float* bqkv = (float*)(ws + 24*MB);  // 12 KB
  u16*   nrm  = (u16*)(ws + 25*MB);    // 16 MB (LN1 out, later LN2 out)
  u16*   qkvb = (u16*)(ws + 41*MB);    // 48 MB
  u16*   attn = (u16*)(ws + 89*MB);    // 16 MB
  float* x2   = (float*)(ws + 105*MB); // 32 MB  (total 137 MB)
  u16*   h1   = (u16*)(ws + 41*MB);    // reuse qkvb+attn (64 MB) after attn

  // fused: weight convert + bias concat + LN1 (independent work, one launch)
  k_prep<<<20483, 256, 0, stream>>>(Wq, Wk, Wv, Wo, Wm1, Wm2, bq, bk, bv,
                                    wqkv, wo, wm1, wm2, bqkv, x, g1, b1, nrm);

  const int M = 8192;
  // fused QKV projection (BM=128: grid 768, no tail)
  k_gemm128<0><<<dim3(64*12), 512, 0, stream>>>(nrm, wqkv, bqkv, qkvb, nullptr, M, 3072, 1024, 12);
  // attention (512 threads, QBLK=256, 2 blocks/CU)
  k_flash<<<512, 512, 0, stream>>>(qkvb, attn);
  // out proj + residual (BM=128: grid 256 = full chip)
  k_gemm128<1><<<dim3(64*4), 512, 0, stream>>>(attn, wo, bo, x2, x, M, 1024, 1024, 4);
  // LN2
  k_ln<<<M, 256, 0, stream>>>(x2, g2, b2, nrm);
  // MLP1: h1 = gelu(nrm @ Wm1^T + bm1)
  k_gemm256<2><<<dim3(32*16), 512, 0, stream>>>(nrm, wm1, bm1, h1, nullptr, M, 4096, 1024, 16);
  // MLP2: out = x2 + h1 @ Wm2^T + bm2  (BM=128: grid 256 = full chip)
  k_gemm128<1><<<dim3(64*4), 512, 0, stream>>>(h1, wm2, bm2, d_out, x2, M, 1024, 4096, 4);
}